// Round 5
// baseline (172.219 us; speedup 1.0000x reference)
//
#include <hip/hip_runtime.h>

#define C_CH   1024
#define T_DIM  16384
#define NSTEPS (T_DIM - 16)   // 16368
#define PAD    8
#define TP     (T_DIM + 16)   // 16400
#define CHUNK  128
#define NCHUNK 128            // 128*128 = 16384 >= 16368
#define WARM   256
#define XPADW  21             // LDS row pitch (2-way max conflicts, free per m136)
#define SPADW  21

// ws layout (R2's passing footprint, ~1.06 MiB):
//   [0, 8*T_DIM*sizeof(double))  : double part[8][T_DIM]   (1 MiB)
//   [1 MiB, +TP*4)               : float  cm[TP]
#define WS_CM_OFFSET (8u * T_DIM * sizeof(double))

// ---------------- Kernel 1: per-row-chunk column partial sums (float4) ----------------
__global__ void colsum_partial(const float* __restrict__ inp, double* __restrict__ part) {
    int col4 = (blockIdx.x * 256 + threadIdx.x) * 4;   // 0..16380 step 4
    int rc   = blockIdx.y;                             // 0..7 (row chunk of 128)
    const float* p = inp + (size_t)rc * 128 * T_DIM + col4;
    double ax = 0.0, ay = 0.0, az = 0.0, aw = 0.0;
    #pragma unroll 4
    for (int r = 0; r < 128; ++r) {
        float4 v = *(const float4*)(p + (size_t)r * T_DIM);
        ax += (double)v.x; ay += (double)v.y; az += (double)v.z; aw += (double)v.w;
    }
    double* q = part + (size_t)rc * T_DIM + col4;
    q[0] = ax; q[1] = ay; q[2] = az; q[3] = aw;
}

// ---------------- Kernel 2: reduce partials -> padded column means, + tail copy ----------------
__global__ void colmean_tail(const double* __restrict__ part, const float* __restrict__ inp,
                             float* __restrict__ cm, float* __restrict__ out) {
    int i = blockIdx.x * 256 + threadIdx.x;   // 0..16639
    if (i < TP) {
        float v = 0.0f;
        if (i >= PAD && i < T_DIM + PAD) {
            int col = i - PAD;
            double t = 0.0;
            #pragma unroll
            for (int r = 0; r < 8; ++r) t += part[(size_t)r * T_DIM + col];
            v = (float)(t * (1.0 / 1024.0));        // /1024 is exact
        }
        cm[i] = v;
    }
    if (i < C_CH * 16) {                        // tail columns NSTEPS..T_DIM-1
        int c = i >> 4, j = i & 15;
        size_t idx = (size_t)c * T_DIM + NSTEPS + j;
        out[idx] = inp[idx];
    }
}

// ---------------- Kernel 3: time-chunk scan, LDS-coalesced loads & stores ----------------
__global__ __launch_bounds__(64) void scan_kernel(const float* __restrict__ inp,
                                                  const float* __restrict__ cm,
                                                  float* __restrict__ out) {
    __shared__ float xt[64][XPADW];   // incoming x tile: 64 ch x 16 steps
    __shared__ float st[64][SPADW];   // spike tile:      64 ch x 16 steps

    const int k    = blockIdx.x;                 // time chunk
    const int lane = threadIdx.x;                // channel within block
    const int c0   = blockIdx.y * 64;
    const int t0   = k * CHUNK;
    const int tend = min(t0 + CHUNK, NSTEPS);    // last chunk: 112 steps (mult of 16)
    // warmup start; CLAMPED at 0 (k=1 gets tw=0 -> exact initial state, not speculative)
    const int tw   = (t0 - WARM > 0) ? (t0 - WARM) : 0;

    const float* row = inp + (size_t)(c0 + lane) * T_DIM;

    // cooperative tile mapping: lane -> rows {sr, sr+16, sr+32, sr+48}, cols sc4..sc4+3
    const int sr  = lane >> 2;
    const int sc4 = (lane & 3) << 2;
    const float* srow0 = inp + (size_t)(c0 + sr)      * T_DIM + sc4 + 8;
    const float* srow1 = inp + (size_t)(c0 + sr + 16) * T_DIM + sc4 + 8;
    const float* srow2 = inp + (size_t)(c0 + sr + 32) * T_DIM + sc4 + 8;
    const float* srow3 = inp + (size_t)(c0 + sr + 48) * T_DIM + sc4 + 8;
    float* orow0 = out + (size_t)(c0 + sr)      * T_DIM + sc4;
    float* orow1 = out + (size_t)(c0 + sr + 16) * T_DIM + sc4;
    float* orow2 = out + (size_t)(c0 + sr + 32) * T_DIM + sc4;
    float* orow3 = out + (size_t)(c0 + sr + 48) * T_DIM + sc4;

    // init window registers + running product-sum (tw >= 0 guaranteed)
    float xs[16];
    float win = 0.0f;
    #pragma unroll
    for (int j = 0; j < 16; ++j) {
        int s = tw + j;
        float x = (s >= PAD) ? row[s - PAD] : 0.0f;
        xs[j] = x;
        win = fmaf(x, cm[s], win);
    }

    float w = 1.0f, mem = 0.0f;   // exact when tw==0; warmup-converged otherwise

    // prefetch first stage tile: inp[c][tw+8 .. tw+23]  (16B-aligned)
    float4 r0 = *(const float4*)(srow0 + tw);
    float4 r1 = *(const float4*)(srow1 + tw);
    float4 r2 = *(const float4*)(srow2 + tw);
    float4 r3 = *(const float4*)(srow3 + tw);

    for (int t = tw; t < tend; t += 16) {
        // commit prefetched tile to LDS
        xt[sr][sc4+0]    = r0.x; xt[sr][sc4+1]    = r0.y; xt[sr][sc4+2]    = r0.z; xt[sr][sc4+3]    = r0.w;
        xt[sr+16][sc4+0] = r1.x; xt[sr+16][sc4+1] = r1.y; xt[sr+16][sc4+2] = r1.z; xt[sr+16][sc4+3] = r1.w;
        xt[sr+32][sc4+0] = r2.x; xt[sr+32][sc4+1] = r2.y; xt[sr+32][sc4+2] = r2.z; xt[sr+32][sc4+3] = r2.w;
        xt[sr+48][sc4+0] = r3.x; xt[sr+48][sc4+1] = r3.y; xt[sr+48][sc4+2] = r3.z; xt[sr+48][sc4+3] = r3.w;
        __syncthreads();

        // prefetch next stage (clamped; unused regs on last iter)
        int ts = (t + 16 < tend) ? (t + 16) : t;
        r0 = *(const float4*)(srow0 + ts);
        r1 = *(const float4*)(srow1 + ts);
        r2 = *(const float4*)(srow2 + ts);
        r3 = *(const float4*)(srow3 + ts);

        // 16 recurrence steps; cm[] accesses are wave-uniform (scalar path)
        #pragma unroll
        for (int j = 0; j < 16; ++j) {
            w = fminf(fmaxf(fmaf(0.5f, w, 0.5f * win), -1.0f), 3.0f);
            float x   = xs[j];                       // inp_padded[c, t+j]
            float rst = (mem > 1.0f) ? 1.0f : 0.0f;  // reset from previous mem
            mem = fmaf(0.95f, mem, fmaf(w, x, -rst));
            st[lane][j] = (mem > 1.0f) ? 1.0f : 0.0f;
            float xn = xt[lane][j];                  // inp_padded[c, t+16+j]
            win = fmaf(xn, cm[t + 16 + j], fmaf(-x, cm[t + j], win));
            xs[j] = xn;
        }
        __syncthreads();

        // coalesced full-line writeback (skip warmup stages; wave-uniform branch)
        if (t >= t0) {
            *(float4*)(orow0 + t) = make_float4(st[sr][sc4],    st[sr][sc4+1],    st[sr][sc4+2],    st[sr][sc4+3]);
            *(float4*)(orow1 + t) = make_float4(st[sr+16][sc4], st[sr+16][sc4+1], st[sr+16][sc4+2], st[sr+16][sc4+3]);
            *(float4*)(orow2 + t) = make_float4(st[sr+32][sc4], st[sr+32][sc4+1], st[sr+32][sc4+2], st[sr+32][sc4+3]);
            *(float4*)(orow3 + t) = make_float4(st[sr+48][sc4], st[sr+48][sc4+1], st[sr+48][sc4+2], st[sr+48][sc4+3]);
        }
        __syncthreads();
    }
}

extern "C" void kernel_launch(void* const* d_in, const int* in_sizes, int n_in,
                              void* d_out, int out_size, void* d_ws, size_t ws_size,
                              hipStream_t stream) {
    const float* inp = (const float*)d_in[0];
    float* out = (float*)d_out;
    double* part = (double*)d_ws;
    float* cm = (float*)((char*)d_ws + WS_CM_OFFSET);

    colsum_partial<<<dim3(T_DIM / 1024, 8), 256, 0, stream>>>(inp, part);
    colmean_tail<<<dim3(65), 256, 0, stream>>>(part, inp, cm, out);
    scan_kernel<<<dim3(NCHUNK, C_CH / 64), 64, 0, stream>>>(inp, cm, out);
}

// Round 6
// 161.294 us; speedup vs baseline: 1.0677x; 1.0677x over previous
//
#include <hip/hip_runtime.h>

#define C_CH   1024
#define T_DIM  16384
#define NSTEPS (T_DIM - 16)   // 16368
#define PAD    8
#define TP     (T_DIM + 16)   // 16400
#define CHUNK  512
#define NCHUNK 32             // 32*512 = 16384 >= 16368
#define WARM   256
#define LPITCH 17             // LDS row pitch (odd -> <=2-way conflicts, free per m136)

// ws layout (R2/R5's passing footprint, ~1.06 MiB):
//   [0, 8*T_DIM*sizeof(double))  : double part[8][T_DIM]   (1 MiB)
//   [1 MiB, +TP*4)               : float  cm[TP]
#define WS_CM_OFFSET (8u * T_DIM * sizeof(double))

// ---------------- Kernel 1: column partial sums, 512 blocks ----------------
__global__ void colsum_partial(const float* __restrict__ inp, double* __restrict__ part) {
    int col = blockIdx.x * 256 + threadIdx.x;   // 0..16383  (grid.x = 64)
    int rc  = blockIdx.y;                       // 0..7  (row chunk of 128)
    const float* p = inp + (size_t)rc * 128 * T_DIM + col;
    double a0=0,a1=0,a2=0,a3=0,a4=0,a5=0,a6=0,a7=0;
    #pragma unroll
    for (int r = 0; r < 128; r += 8) {
        a0 += (double)p[(size_t)(r+0) * T_DIM];
        a1 += (double)p[(size_t)(r+1) * T_DIM];
        a2 += (double)p[(size_t)(r+2) * T_DIM];
        a3 += (double)p[(size_t)(r+3) * T_DIM];
        a4 += (double)p[(size_t)(r+4) * T_DIM];
        a5 += (double)p[(size_t)(r+5) * T_DIM];
        a6 += (double)p[(size_t)(r+6) * T_DIM];
        a7 += (double)p[(size_t)(r+7) * T_DIM];
    }
    part[(size_t)rc * T_DIM + col] = ((a0+a1)+(a2+a3)) + ((a4+a5)+(a6+a7));
}

// ---------------- Kernel 2: reduce partials -> padded column means, + tail copy ----------------
__global__ void colmean_tail(const double* __restrict__ part, const float* __restrict__ inp,
                             float* __restrict__ cm, float* __restrict__ out) {
    int i = blockIdx.x * 256 + threadIdx.x;   // 0..16639
    if (i < TP) {
        float v = 0.0f;
        if (i >= PAD && i < T_DIM + PAD) {
            int col = i - PAD;
            double t = 0.0;
            #pragma unroll
            for (int r = 0; r < 8; ++r) t += part[(size_t)r * T_DIM + col];
            v = (float)(t * (1.0 / 1024.0));        // /1024 is exact
        }
        cm[i] = v;
    }
    if (i < C_CH * 16) {                        // tail columns NSTEPS..T_DIM-1
        int c = i >> 4, j = i & 15;
        size_t idx = (size_t)c * T_DIM + NSTEPS + j;
        out[idx] = inp[idx];
    }
}

// ---------------- Kernel 3: time-chunk scan, 128 channels/block, fully coalesced ----------------
__global__ __launch_bounds__(128) void scan_kernel(const float* __restrict__ inp,
                                                   const float* __restrict__ cm,
                                                   float* __restrict__ out) {
    __shared__ float xt[128][LPITCH];   // staged x tile: 128 ch x 16 steps
    __shared__ float st[128][LPITCH];   // spike tile:    128 ch x 16 steps

    const int k    = blockIdx.x;                 // time chunk 0..31
    const int lane = threadIdx.x;                // channel within block (0..127)
    const int c0   = blockIdx.y * 128;
    const int t0   = k * CHUNK;
    const int tend = min(t0 + CHUNK, NSTEPS);    // last chunk: 496 steps (mult of 16)
    const int tw   = (t0 - WARM > 0) ? (t0 - WARM) : 0;   // clamped warmup start (mult of 16)

    // cooperative tile mapping: tid -> rows {sr, sr+32, sr+64, sr+96}, cols sc4..sc4+3
    const int sr  = lane >> 2;            // 0..31
    const int sc4 = (lane & 3) << 2;      // 0,4,8,12
    const float* srow0 = inp + (size_t)(c0 + sr)      * T_DIM + sc4 + 8;
    const float* srow1 = inp + (size_t)(c0 + sr + 32) * T_DIM + sc4 + 8;
    const float* srow2 = inp + (size_t)(c0 + sr + 64) * T_DIM + sc4 + 8;
    const float* srow3 = inp + (size_t)(c0 + sr + 96) * T_DIM + sc4 + 8;
    float* orow0 = out + (size_t)(c0 + sr)      * T_DIM + sc4;
    float* orow1 = out + (size_t)(c0 + sr + 32) * T_DIM + sc4;
    float* orow2 = out + (size_t)(c0 + sr + 64) * T_DIM + sc4;
    float* orow3 = out + (size_t)(c0 + sr + 96) * T_DIM + sc4;

    // ---- pre-stage: tile of padded positions [tw..tw+15] = rows tw-8..tw+7 ----
    // validity depends only on (tw, sc4): tw==0 && sc4<8 -> left zero-pad
    float4 r0, r1, r2, r3;
    if (tw == 0 && sc4 < 8) {
        r0 = r1 = r2 = r3 = make_float4(0.f, 0.f, 0.f, 0.f);
    } else {
        r0 = *(const float4*)(srow0 + tw - 16);
        r1 = *(const float4*)(srow1 + tw - 16);
        r2 = *(const float4*)(srow2 + tw - 16);
        r3 = *(const float4*)(srow3 + tw - 16);
    }
    xt[sr][sc4+0]    = r0.x; xt[sr][sc4+1]    = r0.y; xt[sr][sc4+2]    = r0.z; xt[sr][sc4+3]    = r0.w;
    xt[sr+32][sc4+0] = r1.x; xt[sr+32][sc4+1] = r1.y; xt[sr+32][sc4+2] = r1.z; xt[sr+32][sc4+3] = r1.w;
    xt[sr+64][sc4+0] = r2.x; xt[sr+64][sc4+1] = r2.y; xt[sr+64][sc4+2] = r2.z; xt[sr+64][sc4+3] = r2.w;
    xt[sr+96][sc4+0] = r3.x; xt[sr+96][sc4+1] = r3.y; xt[sr+96][sc4+2] = r3.z; xt[sr+96][sc4+3] = r3.w;
    __syncthreads();

    float xs[16];
    float win = 0.0f;
    #pragma unroll
    for (int j = 0; j < 16; ++j) {
        float x = xt[lane][j];
        xs[j] = x;
        win = fmaf(x, cm[tw + j], win);
    }
    float w = 1.0f, mem = 0.0f;   // exact when tw==0; warmup-converged otherwise
    __syncthreads();

    // prefetch first in-loop tile: padded positions [tw+16..tw+31]
    r0 = *(const float4*)(srow0 + tw);
    r1 = *(const float4*)(srow1 + tw);
    r2 = *(const float4*)(srow2 + tw);
    r3 = *(const float4*)(srow3 + tw);

    for (int t = tw; t < tend; t += 16) {
        // commit prefetched tile to LDS
        xt[sr][sc4+0]    = r0.x; xt[sr][sc4+1]    = r0.y; xt[sr][sc4+2]    = r0.z; xt[sr][sc4+3]    = r0.w;
        xt[sr+32][sc4+0] = r1.x; xt[sr+32][sc4+1] = r1.y; xt[sr+32][sc4+2] = r1.z; xt[sr+32][sc4+3] = r1.w;
        xt[sr+64][sc4+0] = r2.x; xt[sr+64][sc4+1] = r2.y; xt[sr+64][sc4+2] = r2.z; xt[sr+64][sc4+3] = r2.w;
        xt[sr+96][sc4+0] = r3.x; xt[sr+96][sc4+1] = r3.y; xt[sr+96][sc4+2] = r3.z; xt[sr+96][sc4+3] = r3.w;
        __syncthreads();

        // prefetch next stage (clamped on last iter; values unused then)
        int ts = (t + 16 < tend) ? (t + 16) : t;
        r0 = *(const float4*)(srow0 + ts);
        r1 = *(const float4*)(srow1 + ts);
        r2 = *(const float4*)(srow2 + ts);
        r3 = *(const float4*)(srow3 + ts);

        // 16 recurrence steps; cm[] reads are uniform (scalar path)
        #pragma unroll
        for (int j = 0; j < 16; ++j) {
            w = fminf(fmaxf(fmaf(0.5f, w, 0.5f * win), -1.0f), 3.0f);
            float x   = xs[j];                       // inp_padded[c, t+j]
            float rst = (mem > 1.0f) ? 1.0f : 0.0f;  // reset from previous mem
            mem = fmaf(0.95f, mem, fmaf(w, x, -rst));
            st[lane][j] = (mem > 1.0f) ? 1.0f : 0.0f;
            float xn = xt[lane][j];                  // inp_padded[c, t+16+j]
            win = fmaf(xn, cm[t + 16 + j], fmaf(-x, cm[t + j], win));
            xs[j] = xn;
        }
        __syncthreads();

        // coalesced full-line writeback (warmup stages skipped; wave-uniform branch)
        if (t >= t0) {
            *(float4*)(orow0 + t) = make_float4(st[sr][sc4],    st[sr][sc4+1],    st[sr][sc4+2],    st[sr][sc4+3]);
            *(float4*)(orow1 + t) = make_float4(st[sr+32][sc4], st[sr+32][sc4+1], st[sr+32][sc4+2], st[sr+32][sc4+3]);
            *(float4*)(orow2 + t) = make_float4(st[sr+64][sc4], st[sr+64][sc4+1], st[sr+64][sc4+2], st[sr+64][sc4+3]);
            *(float4*)(orow3 + t) = make_float4(st[sr+96][sc4], st[sr+96][sc4+1], st[sr+96][sc4+2], st[sr+96][sc4+3]);
        }
        __syncthreads();
    }
}

extern "C" void kernel_launch(void* const* d_in, const int* in_sizes, int n_in,
                              void* d_out, int out_size, void* d_ws, size_t ws_size,
                              hipStream_t stream) {
    const float* inp = (const float*)d_in[0];
    float* out = (float*)d_out;
    double* part = (double*)d_ws;
    float* cm = (float*)((char*)d_ws + WS_CM_OFFSET);

    colsum_partial<<<dim3(T_DIM / 256, 8), 256, 0, stream>>>(inp, part);
    colmean_tail<<<dim3(65), 256, 0, stream>>>(part, inp, cm, out);
    scan_kernel<<<dim3(NCHUNK, C_CH / 128), 128, 0, stream>>>(inp, cm, out);
}

// Round 7
// 159.125 us; speedup vs baseline: 1.0823x; 1.0136x over previous
//
#include <hip/hip_runtime.h>

#define C_CH   1024
#define T_DIM  16384
#define NSTEPS (T_DIM - 16)   // 16368
#define PAD    8
#define TP     (T_DIM + 16)   // 16400
#define CHUNK  256
#define NCHUNK 64             // 64*256 = 16384 >= 16368
#define WARM   256
#define STEP   32             // time steps per stage (128B per row per stage)
#define LP     33             // LDS pitch: (lane*33+j)%32 = (lane+j)%32 -> 2-way, free

// ws layout (passing footprint, ~1.06 MiB):
//   [0, 8*T_DIM*sizeof(double))  : double part[8][T_DIM]
//   [1 MiB, +TP*4)               : float  cm[TP]
#define WS_CM_OFFSET (8u * T_DIM * sizeof(double))

// ---------------- Kernel 1: column partial sums ----------------
__global__ void colsum_partial(const float* __restrict__ inp, double* __restrict__ part) {
    int col = blockIdx.x * 256 + threadIdx.x;   // 0..16383
    int rc  = blockIdx.y;                       // 0..7
    const float* p = inp + (size_t)rc * 128 * T_DIM + col;
    double a0=0,a1=0,a2=0,a3=0,a4=0,a5=0,a6=0,a7=0;
    #pragma unroll
    for (int r = 0; r < 128; r += 8) {
        a0 += (double)p[(size_t)(r+0) * T_DIM];
        a1 += (double)p[(size_t)(r+1) * T_DIM];
        a2 += (double)p[(size_t)(r+2) * T_DIM];
        a3 += (double)p[(size_t)(r+3) * T_DIM];
        a4 += (double)p[(size_t)(r+4) * T_DIM];
        a5 += (double)p[(size_t)(r+5) * T_DIM];
        a6 += (double)p[(size_t)(r+6) * T_DIM];
        a7 += (double)p[(size_t)(r+7) * T_DIM];
    }
    part[(size_t)rc * T_DIM + col] = ((a0+a1)+(a2+a3)) + ((a4+a5)+(a6+a7));
}

// ---------------- Kernel 2: reduce partials -> padded column means, + tail copy ----------------
__global__ void colmean_tail(const double* __restrict__ part, const float* __restrict__ inp,
                             float* __restrict__ cm, float* __restrict__ out) {
    int i = blockIdx.x * 256 + threadIdx.x;   // 0..16639
    if (i < TP) {
        float v = 0.0f;
        if (i >= PAD && i < T_DIM + PAD) {
            int col = i - PAD;
            double t = 0.0;
            #pragma unroll
            for (int r = 0; r < 8; ++r) t += part[(size_t)r * T_DIM + col];
            v = (float)(t * (1.0 / 1024.0));        // /1024 is exact
        }
        cm[i] = v;
    }
    if (i < C_CH * 16) {                        // tail columns NSTEPS..T_DIM-1
        int c = i >> 4, j = i & 15;
        size_t idx = (size_t)c * T_DIM + NSTEPS + j;
        out[idx] = inp[idx];
    }
}

// ---------------- Kernel 3: single-wave blocks, 32-step stages, full-sector I/O ----------------
__global__ __launch_bounds__(64) void scan_kernel(const float* __restrict__ inp,
                                                  const float* __restrict__ cm,
                                                  float* __restrict__ out) {
    __shared__ float xt[64][LP];   // staged x tile: 64 ch x 32 steps
    __shared__ float st[64][LP];   // spike tile:    64 ch x 32 steps

    const int k    = blockIdx.x;                 // time chunk 0..63
    const int lane = threadIdx.x;                // channel within block
    const int c0   = blockIdx.y * 64;
    const int t0   = k * CHUNK;
    const int tend = min(t0 + CHUNK, NSTEPS);    // k=63: 16368
    const int tw   = (t0 - WARM > 0) ? (t0 - WARM) : 0;   // mult of 256

    // pre-stage mapping: 16 rows x 16 cols per instr
    const int r16 = lane >> 2;            // 0..15
    const int c4  = (lane & 3) << 2;      // 0,4,8,12
    // main mapping: 8 rows x 32 cols per instr (128B per row)
    const int r8  = lane >> 3;            // 0..7
    const int c8  = (lane & 7) << 2;      // 0,4,...,28

    // ---- pre-stage: xt[.][0..15] = padded positions [tw..tw+15] = rows [tw-8..tw+7] ----
    {
        bool zf = (tw == 0) && (c4 < 8);  // left zero-pad
        #pragma unroll
        for (int h = 0; h < 4; ++h) {
            int r = r16 + 16 * h;
            float4 v = make_float4(0.f, 0.f, 0.f, 0.f);
            if (!zf) v = *(const float4*)(inp + (size_t)(c0 + r) * T_DIM + (tw - 8 + c4));
            xt[r][c4+0] = v.x; xt[r][c4+1] = v.y; xt[r][c4+2] = v.z; xt[r][c4+3] = v.w;
        }
    }
    __syncthreads();

    // delay line dl[j] = inp_padded[c, t+j] for the current window
    float dl[16];
    float win = 0.0f;
    #pragma unroll
    for (int j = 0; j < 16; ++j) {
        float x = xt[lane][j];
        dl[j] = x;
        win = fmaf(x, cm[tw + j], win);
    }
    float w = 1.0f, mem = 0.0f;   // exact when tw==0; warmup-converged otherwise
    __syncthreads();

    // per-row pointers (main mapping); gp has +8 (pad->row) and +c8 baked in
    const float* gp[8];
    float*       op[8];
    #pragma unroll
    for (int g = 0; g < 8; ++g) {
        gp[g] = inp + (size_t)(c0 + r8 + 8 * g) * T_DIM + 8 + c8;
        op[g] = out + (size_t)(c0 + r8 + 8 * g) * T_DIM + c8;
    }

    // prefetch first tile: padded [tw+16..tw+47] -> load at gp + tw (rows tw+8+c8..+3)
    float4 pf[8];
    {
        int toff = (tw + c8 <= T_DIM - 12) ? tw : 0;   // clamp (values unused when clamped)
        #pragma unroll
        for (int g = 0; g < 8; ++g) pf[g] = *(const float4*)(gp[g] + toff);
    }

    for (int t = tw; t < tend; t += STEP) {
        // commit prefetched tile to LDS (cols 0..31 = padded [t+16..t+47])
        #pragma unroll
        for (int g = 0; g < 8; ++g) {
            int r = r8 + 8 * g;
            xt[r][c8+0] = pf[g].x; xt[r][c8+1] = pf[g].y; xt[r][c8+2] = pf[g].z; xt[r][c8+3] = pf[g].w;
        }
        __syncthreads();

        // prefetch next stage (clamped per-lane; clamped values never used)
        {
            int tn = t + STEP;
            int toff = (tn < tend && tn + c8 <= T_DIM - 12) ? tn : 0;
            #pragma unroll
            for (int g = 0; g < 8; ++g) pf[g] = *(const float4*)(gp[g] + toff);
        }

        // 32 recurrence steps (jn<32 only on the last chunk's final stage; uniform guard)
        int jn = tend - t;
        #pragma unroll
        for (int j = 0; j < STEP; ++j) {
            if (j < jn) {
                w = fminf(fmaxf(fmaf(0.5f, w, 0.5f * win), -1.0f), 3.0f);
                float x   = dl[j & 15];                  // inp_padded[c, t+j]
                float rst = (mem > 1.0f) ? 1.0f : 0.0f;  // reset from previous mem
                mem = fmaf(0.95f, mem, fmaf(w, x, -rst));
                st[lane][j] = (mem > 1.0f) ? 1.0f : 0.0f;
                float xn = xt[lane][j];                  // inp_padded[c, t+16+j]
                win = fmaf(xn, cm[t + 16 + j], fmaf(-x, cm[t + j], win));
                dl[j & 15] = xn;
            }
        }
        __syncthreads();

        // full-sector writeback: 128B per row per stage; warmup stages skipped
        if (t >= t0) {
            #pragma unroll
            for (int g = 0; g < 8; ++g) {
                int r = r8 + 8 * g;
                if (t + c8 < tend)   // uniform-true except last partial stage
                    *(float4*)(op[g] + t) = make_float4(st[r][c8], st[r][c8+1], st[r][c8+2], st[r][c8+3]);
            }
        }
        __syncthreads();
    }
}

extern "C" void kernel_launch(void* const* d_in, const int* in_sizes, int n_in,
                              void* d_out, int out_size, void* d_ws, size_t ws_size,
                              hipStream_t stream) {
    const float* inp = (const float*)d_in[0];
    float* out = (float*)d_out;
    double* part = (double*)d_ws;
    float* cm = (float*)((char*)d_ws + WS_CM_OFFSET);

    colsum_partial<<<dim3(T_DIM / 256, 8), 256, 0, stream>>>(inp, part);
    colmean_tail<<<dim3(65), 256, 0, stream>>>(part, inp, cm, out);
    scan_kernel<<<dim3(NCHUNK, C_CH / 64), 64, 0, stream>>>(inp, cm, out);
}